// Round 9
// baseline (1384.837 us; speedup 1.0000x reference)
//
#include <hip/hip_runtime.h>

typedef unsigned short u16;
typedef __bf16 bf16x8 __attribute__((ext_vector_type(8)));
typedef float f32x4 __attribute__((ext_vector_type(4)));

__device__ __forceinline__ u16 f2b(float f) {
    unsigned u = __builtin_bit_cast(unsigned, f);
    unsigned r = (u + 0x7fffu + ((u >> 16) & 1u)) >> 16;
    return (u16)r;
}
#if __has_builtin(__builtin_amdgcn_cvt_pk_bf16_f32)
typedef __bf16 bf16x2_t __attribute__((ext_vector_type(2)));
__device__ __forceinline__ unsigned pk2(float a, float b) {
    return __builtin_bit_cast(unsigned, __builtin_amdgcn_cvt_pk_bf16_f32(a, b));
}
#else
__device__ __forceinline__ unsigned pk2(float a, float b) {
    return (unsigned)f2b(a) | ((unsigned)f2b(b) << 16);
}
#endif
#if __has_builtin(__builtin_amdgcn_exp2f)
#define EXP2F(x) __builtin_amdgcn_exp2f(x)
#else
#define EXP2F(x) exp2f(x)
#endif

// async global->LDS 16B/lane; lds dest is wave-uniform base (+lane*16 by HW);
// global source IS per-lane (m173) -- swizzled layouts via pre-swizzled source.
__device__ __forceinline__ void gl_lds16(const u16* g, u16* l) {
    __builtin_amdgcn_global_load_lds(
        (const __attribute__((address_space(1))) unsigned*)(const void*)g,
        (__attribute__((address_space(3))) unsigned*)(void*)l, 16, 0, 0);
}

// ---------------- device-side sync state ----------------
// [0] = grid-barrier counter, [16] = qkv work-ticket (separate cachelines).
// Zeroed by k_init each launch (device store; kernel boundary = system release;
// avoids hipGetSymbolAddress/memset unknowns that may have killed r6).
__device__ unsigned g_sync[32];

__global__ void k_init() {
    if (threadIdx.x < 32) g_sync[threadIdx.x] = 0;
}

// ---------------- manual grid barrier ----------------
// r6 post-mortem: RELAXED agent poll can be served from non-coherent L1
// forever -> infinite spin -> container timeout. Fix: ACQUIRE agent load
// (L1-invalidating cache ops per AMDGPU memory model). Arrive: threadfence
// (preceding __syncthreads drained all waves' vmcnt; fence cache-ops are
// cache-wide) + RELEASE add. Spin bounded at ~20ms: if barrier is broken the
// bench completes with garbage (diagnosable) instead of hanging the container.
// Residency: 1024 blocks x (32KB LDS, VGPR<=128 via launch_bounds(256,4))
// = exactly 4/CU, so all blocks co-resident by construction.
__device__ __forceinline__ void grid_barrier(unsigned target) {
    __syncthreads();
    if (threadIdx.x == 0) {
        __threadfence();
        __hip_atomic_fetch_add(&g_sync[0], 1u, __ATOMIC_RELEASE,
                               __HIP_MEMORY_SCOPE_AGENT);
        int spins = 0;
        while (__hip_atomic_load(&g_sync[0], __ATOMIC_ACQUIRE,
                                 __HIP_MEMORY_SCOPE_AGENT) < target &&
               ++spins < 60000)
            __builtin_amdgcn_s_sleep(4);
        __threadfence();
    }
    __syncthreads();
}

// -------- 64x64 transpose+convert: in[R][C] f32 -> out[C][R] bf16 --------
__device__ __forceinline__ void transpose64(const float* __restrict__ in,
                                            u16* __restrict__ out, int R, int C,
                                            int tr, int tc, int tid, u16 (*tile)[72]) {
    for (int i = tid; i < 4096; i += 256) {
        int r = i >> 6, c = i & 63;
        tile[c][r] = f2b(in[(size_t)(tr + r) * C + tc + c]);
    }
    __syncthreads();
    for (int i = tid; i < 4096; i += 256) {
        int r = i >> 6, c = i & 63;
        out[(size_t)(tc + r) * R + tr + c] = tile[r][c];
    }
    __syncthreads();  // LDS tile safe for any later reuse
}

// ------- 128x128xK bf16 MFMA mainloop, BK=64 (2x32 stages per barrier pair) -------
__device__ __forceinline__ void gemm_mainloop(const u16* __restrict__ Ab,
                                              const u16* __restrict__ Bb, int K,
                                              u16* As, u16* Bs, int tid,
                                              f32x4 (&acc)[4][4]) {
    const int wave = tid >> 6, lane = tid & 63;
    const int col = lane & 15, quad = lane >> 4;
    const int wm = wave >> 1, wn = wave & 1;
    const int lrow = lane >> 2, lk = (lane & 3) * 8;
    u16* ldsA0 = As + (wave * 16) * 32;  // wave-uniform segment bases
    u16* ldsA1 = As + (64 + wave * 16) * 32;
    u16* ldsB0 = Bs + (wave * 16) * 32;
    u16* ldsB1 = Bs + (64 + wave * 16) * 32;
    const u16* gA0 = Ab + (size_t)(wave * 16 + lrow) * K + lk;
    const u16* gA1 = gA0 + (size_t)64 * K;
    const u16* gB0 = Bb + (size_t)(wave * 16 + lrow) * K + lk;
    const u16* gB1 = gB0 + (size_t)64 * K;
    for (int k0 = 0; k0 < K; k0 += 64) {
        if (k0) __syncthreads();
#pragma unroll
        for (int kh = 0; kh < 2; ++kh) {
            int ko = k0 + kh * 32;
            gl_lds16(gA0 + ko, ldsA0 + kh * 4096);
            gl_lds16(gA1 + ko, ldsA1 + kh * 4096);
            gl_lds16(gB0 + ko, ldsB0 + kh * 4096);
            gl_lds16(gB1 + ko, ldsB1 + kh * 4096);
        }
        __syncthreads();  // compiler drains vmcnt(0) before s_barrier
#pragma unroll
        for (int kh = 0; kh < 2; ++kh) {
            bf16x8 af[4], bfr[4];
#pragma unroll
            for (int mt = 0; mt < 4; ++mt)
                af[mt] = *(const bf16x8*)(As + kh * 4096 +
                                          (wm * 64 + mt * 16 + col) * 32 + quad * 8);
#pragma unroll
            for (int nt = 0; nt < 4; ++nt)
                bfr[nt] = *(const bf16x8*)(Bs + kh * 4096 +
                                           (wn * 64 + nt * 16 + col) * 32 + quad * 8);
#pragma unroll
            for (int mt = 0; mt < 4; ++mt)
#pragma unroll
                for (int nt = 0; nt < 4; ++nt)
                    acc[mt][nt] = __builtin_amdgcn_mfma_f32_16x16x32_bf16(
                        af[mt], bfr[nt], acc[mt][nt], 0, 0, 0);
        }
    }
}

// ---------------- QKV GEMM tile + bias + RoPE + head reshape ----------------
// Q additionally prescaled by 0.125*log2(e) so attention softmax is pure exp2.
__device__ __forceinline__ void qkv_tile(int bx, int by, const u16* __restrict__ A,
                                         const u16* __restrict__ Bt,
                                         const float* __restrict__ bias,
                                         const float2* __restrict__ tab,
                                         u16* __restrict__ Qr, u16* __restrict__ Kr,
                                         u16* __restrict__ Vt, u16* smem, int tid) {
    u16* As = smem;
    u16* Bs = smem + 8192;
    int lane = tid & 63, wave = tid >> 6;
    int col = lane & 15, quad = lane >> 4;
    int wm = wave >> 1, wn = wave & 1;
    int mBase = by * 128;
    int nBase = bx * 128;
    f32x4 acc[4][4] = {};
    gemm_mainloop(A + (size_t)mBase * 1024, Bt + (size_t)nBase * 1024, 1024, As, Bs,
                  tid, acc);

    int region = nBase >> 10;  // 0=q, 1=k, 2=v (block-uniform)
    int n64 = nBase + wn * 64;
    int h = (n64 & 1023) >> 6;
    if (region < 2) {
        __syncthreads();  // mainloop LDS reads complete before tile overwrite
        float qs = (region == 0) ? 0.18033688011112042f : 1.0f;  // 0.125*log2(e)
#pragma unroll
        for (int nt = 0; nt < 2; ++nt) {
            int d1 = nt * 16 + col;  // 0..31
            float b1 = bias[n64 + d1];
            float b2 = bias[n64 + d1 + 32];
            int nl = wn * 64 + nt * 16 + col;
#pragma unroll
            for (int mt = 0; mt < 4; ++mt) {
                int mlb = wm * 64 + mt * 16 + quad * 4;
#pragma unroll
                for (int r = 0; r < 4; ++r) {
                    int mloc = mlb + r;
                    int s = (mBase + mloc) & 2047;
                    float2 t = tab[s * 32 + d1];
                    float t1 = acc[mt][nt][r] + b1;
                    float t2 = acc[mt][nt + 2][r] + b2;
                    int sw = (mloc & 7) << 3;  // 16B-chunk XOR swizzle
                    smem[mloc * 128 + (nl ^ sw)] = f2b((t1 * t.x - t2 * t.y) * qs);
                    smem[mloc * 128 + ((nl + 32) ^ sw)] = f2b((t2 * t.x + t1 * t.y) * qs);
                }
            }
        }
        __syncthreads();
        u16* outp = (region == 0) ? Qr : Kr;
#pragma unroll
        for (int p = 0; p < 8; ++p) {
            int lin = p * 256 + tid;   // 0..2047
            int mloc = lin >> 4;       // 0..127
            int c8 = (lin & 15) << 3;  // 0..120
            uint4 v = *(const uint4*)(smem + mloc * 128 + (c8 ^ ((mloc & 7) << 3)));
            int m = mBase + mloc;
            int s = m & 2047, b = m >> 11;
            int ng = (nBase & 1023) + c8;  // col within region
            *(uint4*)(outp + ((size_t)((b * 16 + (ng >> 6)) * 2048 + s)) * 64 +
                      (ng & 63)) = v;
        }
    } else {
        int b = mBase >> 11;     // block-uniform (mBase multiple of 128)
        int sb0 = mBase & 2047;  // s of tile row 0
#pragma unroll
        for (int nt = 0; nt < 4; ++nt) {
            int d = nt * 16 + col;
            float bv = bias[n64 + d];
            u16* vrow = Vt + ((size_t)((b * 16 + h) * 64 + d)) * 2048;
#pragma unroll
            for (int mt = 0; mt < 4; ++mt) {
                int s = sb0 + wm * 64 + mt * 16 + quad * 4;  // 4-aligned
                uint2 w;
                w.x = pk2(acc[mt][nt][0] + bv, acc[mt][nt][1] + bv);
                w.y = pk2(acc[mt][nt][2] + bv, acc[mt][nt][3] + bv);
                *(uint2*)(vrow + s) = w;
            }
        }
    }
}

// ---- attn K/V tile staging: async DMA, chunk-XOR swizzled (rule #21) ----
__device__ __forceinline__ void stage_kv(const u16* __restrict__ Kt,
                                         const u16* __restrict__ Vtb, u16* KsB,
                                         u16* VsB, int wave, int lane) {
    int lr = lane >> 3;  // row within 8-row segment
    int lc = lane & 7;   // chunk slot
#pragma unroll
    for (int i = 0; i < 2; ++i) {
        int s = wave * 2 + i;  // K segment 0..7
        int r = s * 8 + lr;    // local key row 0..63
        int key = (r & 3) | (((r >> 3) & 1) << 2);
        gl_lds16(Kt + (size_t)r * 64 + ((lc ^ key) << 3), KsB + s * 512);
    }
#pragma unroll
    for (int i = 0; i < 2; ++i) {
        int s = wave * 2 + i;  // V segment 0..7
        int d = s * 8 + lr;    // local d row 0..63
        int key = d & 7;
        gl_lds16(Vtb + (size_t)d * 2048 + ((lc ^ key) << 3), VsB + s * 512);
    }
}

// ------------- flash attention block (r7-proven sequential two-phase) -------------
// Uniform 33 key-tile iters/block -> ideal for barrier-synced phases.
__device__ __forceinline__ void attn_block(int id, const u16* __restrict__ Qr,
                                           const u16* __restrict__ Kr,
                                           const u16* __restrict__ Vt,
                                           u16* __restrict__ O, u16* smem, int tid) {
    u16* KsBuf = smem;         // [2][4096]
    u16* VsBuf = smem + 8192;  // [2][4096]
    int wave = tid >> 6, lane = tid & 63;
    int col = lane & 15, quad = lane >> 4;
    int xcd = id & 7, w = id >> 3;  // w: 0..127 within XCD
    int head = xcd * 8 + (w & 7);   // 0..63 (head's 16 blocks share one XCD L2)
    int tsel = w >> 3;              // 0..15
    int b = head >> 4, h = head & 15;
    size_t headQ = (size_t)head * 2048 * 64;
    size_t headV = (size_t)head * 64 * 2048;
    int prow = (col >> 2) * 8 + (col & 3);  // permuted row within 32
    int ck = col & 7;                       // read-side swizzle key

#pragma unroll 1
    for (int phase = 0; phase < 2; ++phase) {
        int T = phase ? tsel : 31 - tsel;  // key-tile count-1 for this q-tile
        int myq = T * 64 + wave * 16 + col;
        const u16* qp = Qr + headQ + (size_t)myq * 64;
        bf16x8 aq0 = *(const bf16x8*)(qp + quad * 8);
        bf16x8 aq1 = *(const bf16x8*)(qp + 32 + quad * 8);
        f32x4 o[4] = {};
        float l = 0.f;

        stage_kv(Kr + headQ, Vt + headV, KsBuf, VsBuf, wave, lane);
        __syncthreads();  // drains vmcnt(0): tile 0 deposited

        for (int j = 0; j <= T; ++j) {
            int cur = j & 1;
            if (j < T)  // async prefetch tile j+1 into other buffer
                stage_kv(Kr + headQ + ((size_t)(j + 1) << 12),
                         Vt + headV + (j + 1) * 64, KsBuf + (cur ^ 1) * 4096,
                         VsBuf + (cur ^ 1) * 4096, wave, lane);
            const u16* KsC = KsBuf + cur * 4096;
            const u16* VsC = VsBuf + cur * 4096;
            f32x4 s[4];
            __builtin_amdgcn_s_setprio(1);
#pragma unroll
            for (int nt = 0; nt < 4; ++nt) {
                const u16* kp = KsC + ((nt & 1) * 32 + (nt >> 1) * 4 + prow) * 64;
                bf16x8 ak0 = *(const bf16x8*)(kp + ((quad ^ ck) << 3));
                bf16x8 ak1 = *(const bf16x8*)(kp + (((quad + 4) ^ ck) << 3));
                f32x4 z = {};
                z = __builtin_amdgcn_mfma_f32_16x16x32_bf16(ak0, aq0, z, 0, 0, 0);
                s[nt] = __builtin_amdgcn_mfma_f32_16x16x32_bf16(ak1, aq1, z, 0, 0, 0);
            }
            __builtin_amdgcn_s_setprio(0);
            if (j == T) {  // diagonal mask
#pragma unroll
                for (int nt = 0; nt < 4; ++nt) {
                    int keyb = j * 64 + (nt & 1) * 32 + quad * 8 + (nt >> 1) * 4;
#pragma unroll
                    for (int r = 0; r < 4; ++r)
                        if (keyb + r > myq) s[nt][r] = -3.0e38f;
                }
            }
            unsigned P4[8];
#pragma unroll
            for (int nt = 0; nt < 4; ++nt) {
                float p0 = EXP2F(s[nt][0]);
                float p1 = EXP2F(s[nt][1]);
                float p2 = EXP2F(s[nt][2]);
                float p3 = EXP2F(s[nt][3]);
                l += (p0 + p1) + (p2 + p3);
                P4[2 * nt] = pk2(p0, p1);
                P4[2 * nt + 1] = pk2(p2, p3);
            }
            __builtin_amdgcn_s_setprio(1);
#pragma unroll
            for (int kk = 0; kk < 2; ++kk) {
                uint4 bw;
                bw.x = P4[2 * kk];
                bw.y = P4[2 * kk + 1];
                bw.z = P4[2 * kk + 4];
                bw.w = P4[2 * kk + 5];
                bf16x8 bp = __builtin_bit_cast(bf16x8, bw);
#pragma unroll
                for (int mt = 0; mt < 4; ++mt) {
                    bf16x8 av = *(const bf16x8*)(VsC + (mt * 16 + col) * 64 +
                                                 (((kk * 4 + quad) ^ ck) << 3));
                    o[mt] = __builtin_amdgcn_mfma_f32_16x16x32_bf16(av, bp, o[mt], 0, 0, 0);
                }
            }
            __builtin_amdgcn_s_setprio(0);
            __syncthreads();  // drains prefetch DMA + releases buffers
        }
        l += __shfl_xor(l, 16);
        l += __shfl_xor(l, 32);
        float inv = 1.0f / l;
        u16* orow = O + (size_t)(b * 2048 + myq) * 1024 + h * 64;
#pragma unroll
        for (int mt = 0; mt < 4; ++mt) {
            uint2 w2;
            w2.x = pk2(o[mt][0] * inv, o[mt][1] * inv);
            w2.y = pk2(o[mt][2] * inv, o[mt][3] * inv);
            *(uint2*)(orow + mt * 16 + quad * 4) = w2;
        }
    }
}

// ------- 128x64 proj: B stages 64 rows; 4 waves x (32M x 64N); LDS 24KB -------
__device__ __forceinline__ void proj_tile(int bx, int by, const u16* __restrict__ A,
                                          const u16* __restrict__ Bt,
                                          const float* __restrict__ bias,
                                          float* __restrict__ out, u16* smem, int tid) {
    u16* As = smem;         // 2*128*32
    u16* Bs = smem + 8192;  // 2*64*32
    const int wave = tid >> 6, lane = tid & 63;
    const int col = lane & 15, quad = lane >> 4;
    const int lrow = lane >> 2, lk = (lane & 3) * 8;
    int mBase = by * 128, nBase = bx * 64;
    const u16* Ab = A + (size_t)mBase * 1024;
    const u16* Bb = Bt + (size_t)nBase * 1024;
    u16* ldsA0 = As + (wave * 16) * 32;
    u16* ldsA1 = As + (64 + wave * 16) * 32;
    u16* ldsB0 = Bs + (wave * 16) * 32;
    const u16* gA0 = Ab + (size_t)(wave * 16 + lrow) * 1024 + lk;
    const u16* gA1 = gA0 + (size_t)64 * 1024;
    const u16* gB0 = Bb + (size_t)(wave * 16 + lrow) * 1024 + lk;
    f32x4 acc[2][4] = {};
    for (int k0 = 0; k0 < 1024; k0 += 64) {
        if (k0) __syncthreads();
#pragma unroll
        for (int kh = 0; kh < 2; ++kh) {
            int ko = k0 + kh * 32;
            gl_lds16(gA0 + ko, ldsA0 + kh * 4096);
            gl_lds16(gA1 + ko, ldsA1 + kh * 4096);
            gl_lds16(gB0 + ko, ldsB0 + kh * 2048);
        }
        __syncthreads();
#pragma unroll
        for (int kh = 0; kh < 2; ++kh) {
            bf16x8 af[2], bfr[4];
#pragma unroll
            for (int mt = 0; mt < 2; ++mt)
                af[mt] = *(const bf16x8*)(As + kh * 4096 +
                                          (wave * 32 + mt * 16 + col) * 32 + quad * 8);
#pragma unroll
            for (int nt = 0; nt < 4; ++nt)
                bfr[nt] = *(const bf16x8*)(Bs + kh * 2048 +
                                           (nt * 16 + col) * 32 + quad * 8);
#pragma unroll
            for (int mt = 0; mt < 2; ++mt)
#pragma unroll
                for (int nt = 0; nt < 4; ++nt)
                    acc[mt][nt] = __builtin_amdgcn_mfma_f32_16x16x32_bf16(
                        af[mt], bfr[nt], acc[mt][nt], 0, 0, 0);
        }
    }
#pragma unroll
    for (int nt = 0; nt < 4; ++nt) {
        int n = nBase + nt * 16 + col;
        float bv = bias[n];
#pragma unroll
        for (int mt = 0; mt < 2; ++mt) {
            int m = mBase + wave * 32 + mt * 16 + quad * 4;
#pragma unroll
            for (int r = 0; r < 4; ++r)
                out[(size_t)(m + r) * 1024 + n] = acc[mt][nt][r] + bv;
        }
    }
}

// ---------------- fused persistent kernel: prep | qkv | attn | proj ----------------
// 1024 blocks x 256 thr = exactly 4/CU resident (LDS ~32KB, VGPR<=128). Three
// grid barriers replace three kernel transitions (~12us each per r4/r8
// accounting). qkv phase uses atomic work-tickets over 1536 tiles:
// self-balancing under ANY block->CU placement (kills the r2 straggler trap).
// attn: 1024 uniform units, static r7 map; proj: 1024 tiles, 1/block.
__global__ __launch_bounds__(256, 4) void k_fused(
    const float* __restrict__ x, u16* __restrict__ x_bf,
    const float* __restrict__ w_qkv, u16* __restrict__ wqkvT,
    const float* __restrict__ w_proj, u16* __restrict__ wprojT,
    float2* __restrict__ tab, const float* __restrict__ b_qkv,
    const float* __restrict__ b_proj, u16* __restrict__ Qr, u16* __restrict__ Kr,
    u16* __restrict__ Vt, u16* __restrict__ AO, float* __restrict__ out) {
    __shared__ __align__(16) u16 smem[16384];  // 32KB, reused by every phase
    __shared__ int s_t;
    int bid = blockIdx.x, tid = threadIdx.x;

    // ---- phase 0: prep (grid-stride 5376 units; each block: 4 converts +
    //      1 transpose [+ tab for bid<256]) ----
    for (int u = bid; u < 5376; u += 1024) {
        if (u < 4096) {  // x: fp32 -> bf16, 8 elems/thread
            int i = u * 256 + tid;
            const float4* p = (const float4*)(x + (size_t)i * 8);
            float4 a = p[0], b = p[1];
            u16 t[8] = {f2b(a.x), f2b(a.y), f2b(a.z), f2b(a.w),
                        f2b(b.x), f2b(b.y), f2b(b.z), f2b(b.w)};
            *(uint4*)(x_bf + (size_t)i * 8) = *(const uint4*)t;
        } else if (u < 4864) {  // w_qkv [1024][3072] -> wqkvT [3072][1024]
            int q = u - 4096;
            transpose64(w_qkv, wqkvT, 1024, 3072, (q / 48) * 64, (q % 48) * 64, tid,
                        (u16(*)[72])smem);
        } else if (u < 5120) {  // w_proj [1024][1024] -> wprojT
            int q = u - 4864;
            transpose64(w_proj, wprojT, 1024, 1024, (q / 16) * 64, (q % 16) * 64, tid,
                        (u16(*)[72])smem);
        } else {  // tab[s*32+d] = (cos,sin)(s * 10000^(-d/32))
            int i = (u - 5120) * 256 + tid;  // 0..65535
            int s = i >> 5, d = i & 31;
            const float C0 = 0.4152410118609203f;  // log2(10000)/32
            float inv_freq = exp2f(-C0 * (float)d);
            float sn, cs;
            sincosf((float)s * inv_freq, &sn, &cs);
            tab[i] = make_float2(cs, sn);
        }
    }
    grid_barrier(1024);

    // ---- phase 1: QKV GEMM + RoPE, ticket-scheduled over 1536 tiles ----
    for (;;) {
        if (tid == 0)
            s_t = (int)__hip_atomic_fetch_add(&g_sync[16], 1u, __ATOMIC_RELAXED,
                                              __HIP_MEMORY_SCOPE_AGENT);
        __syncthreads();  // broadcast ticket; also fences prev tile's smem reads
        int t = s_t;
        if (t >= 1536) break;
        qkv_tile(t % 24, t / 24, x_bf, wqkvT, b_qkv, tab, Qr, Kr, Vt, smem, tid);
    }
    grid_barrier(2048);

    // ---- phase 2: flash attention (1024 uniform blocks, r7 body) ----
    attn_block(bid, Qr, Kr, Vt, AO, smem, tid);
    grid_barrier(3072);

    // ---- phase 3: output projection (1024 x 128x64 tiles, 1 per block) ----
    proj_tile(bid & 15, bid >> 4, AO, wprojT, b_proj, out, smem, tid);
}

// ---------------- launch ----------------
// ws: x_bf@0 (16MB) wqkvT (6MB) wprojT (2MB) Qr Kr Vt AO (16MB each)
// rope table (512KB) aliases AO: written phase 0, read phase 1; AO written phase 2.
extern "C" void kernel_launch(void* const* d_in, const int* in_sizes, int n_in,
                              void* d_out, int out_size, void* d_ws, size_t ws_size,
                              hipStream_t stream) {
    const float* x = (const float*)d_in[0];
    const float* w_qkv = (const float*)d_in[1];
    const float* b_qkv = (const float*)d_in[2];
    const float* w_proj = (const float*)d_in[3];
    const float* b_proj = (const float*)d_in[4];
    float* out = (float*)d_out;
    char* ws = (char*)d_ws;
    u16* x_bf = (u16*)(ws);
    u16* wqkvT = (u16*)(ws + 16777216);
    u16* wprojT = (u16*)(ws + 23068672);
    u16* Qr = (u16*)(ws + 25165824);
    u16* Kr = (u16*)(ws + 41943040);
    u16* Vt = (u16*)(ws + 58720256);
    u16* AO = (u16*)(ws + 75497472);
    float2* tab = (float2*)(ws + 75497472);  // alias AO (dead until attn phase)

    k_init<<<1, 64, 0, stream>>>();
    k_fused<<<1024, 256, 0, stream>>>(x, x_bf, w_qkv, wqkvT, w_proj, wprojT, tab,
                                      b_qkv, b_proj, Qr, Kr, Vt, AO, out);
}

// Round 10
// 254.253 us; speedup vs baseline: 5.4467x; 5.4467x over previous
//
#include <hip/hip_runtime.h>

typedef unsigned short u16;
typedef __bf16 bf16x8 __attribute__((ext_vector_type(8)));
typedef float f32x4 __attribute__((ext_vector_type(4)));

__device__ __forceinline__ u16 f2b(float f) {
    unsigned u = __builtin_bit_cast(unsigned, f);
    unsigned r = (u + 0x7fffu + ((u >> 16) & 1u)) >> 16;
    return (u16)r;
}
#if __has_builtin(__builtin_amdgcn_cvt_pk_bf16_f32)
typedef __bf16 bf16x2_t __attribute__((ext_vector_type(2)));
__device__ __forceinline__ unsigned pk2(float a, float b) {
    return __builtin_bit_cast(unsigned, __builtin_amdgcn_cvt_pk_bf16_f32(a, b));
}
#else
__device__ __forceinline__ unsigned pk2(float a, float b) {
    return (unsigned)f2b(a) | ((unsigned)f2b(b) << 16);
}
#endif
#if __has_builtin(__builtin_amdgcn_exp2f)
#define EXP2F(x) __builtin_amdgcn_exp2f(x)
#else
#define EXP2F(x) exp2f(x)
#endif

// async global->LDS 16B/lane; lds dest is wave-uniform base (+lane*16 by HW);
// global source IS per-lane (m173) -- swizzled layouts via pre-swizzled source.
__device__ __forceinline__ void gl_lds16(const u16* g, u16* l) {
    __builtin_amdgcn_global_load_lds(
        (const __attribute__((address_space(1))) unsigned*)(const void*)g,
        (__attribute__((address_space(3))) unsigned*)(void*)l, 16, 0, 0);
}

// -------- 64x64 transpose+convert helper: in[R][C] f32 -> out[C][R] bf16 --------
// Pad 66 (not 72): write bank = (33c)%32 = c%32 -> 2 lanes/bank (free, m136).
// The old 72-pad gave write bank = 4c%32 = 8-way conflict (~2.9x that pass).
__device__ __forceinline__ void transpose64(const float* __restrict__ in,
                                            u16* __restrict__ out, int R, int C,
                                            int tr, int tc, int tid, u16 (*tile)[66]) {
    for (int i = tid; i < 4096; i += 256) {
        int r = i >> 6, c = i & 63;
        tile[c][r] = f2b(in[(size_t)(tr + r) * C + tc + c]);
    }
    __syncthreads();
    for (int i = tid; i < 4096; i += 256) {
        int r = i >> 6, c = i & 63;
        out[(size_t)(tc + r) * R + tr + c] = tile[r][c];
    }
}

// ---------------- fused prep: convert x | transpose wqkv | transpose wproj | rope tab ----
// One launch; tasks independent; branch is block-uniform. Blocks: [0,4096) convert,
// [4096,4864) wqkvT, [4864,5120) wprojT, [5120,5376) rope table.
__global__ __launch_bounds__(256) void k_prep(const float* __restrict__ x,
                                              u16* __restrict__ x_bf,
                                              const float* __restrict__ w_qkv,
                                              u16* __restrict__ wqkvT,
                                              const float* __restrict__ w_proj,
                                              u16* __restrict__ wprojT,
                                              float2* __restrict__ tab) {
    __shared__ u16 tile[64][66];
    int bid = blockIdx.x, tid = threadIdx.x;
    if (bid < 4096) {  // x: fp32 -> bf16, 8 elems/thread
        int i = bid * 256 + tid;
        const float4* p = (const float4*)(x + (size_t)i * 8);
        float4 a = p[0], b = p[1];
        u16 t[8] = {f2b(a.x), f2b(a.y), f2b(a.z), f2b(a.w),
                    f2b(b.x), f2b(b.y), f2b(b.z), f2b(b.w)};
        *(uint4*)(x_bf + (size_t)i * 8) = *(const uint4*)t;
    } else if (bid < 4864) {  // w_qkv [1024][3072] -> wqkvT [3072][1024]
        int q = bid - 4096;
        transpose64(w_qkv, wqkvT, 1024, 3072, (q / 48) * 64, (q % 48) * 64, tid, tile);
    } else if (bid < 5120) {  // w_proj [1024][1024] -> wprojT
        int q = bid - 4864;
        transpose64(w_proj, wprojT, 1024, 1024, (q / 16) * 64, (q % 16) * 64, tid, tile);
    } else {  // tab[s*32+d] = (cos,sin)(s * 10000^(-d/32))
        int i = (bid - 5120) * 256 + tid;  // 0..65535
        int s = i >> 5, d = i & 31;
        const float C0 = 0.4152410118609203f;  // log2(10000)/32
        float inv_freq = exp2f(-C0 * (float)d);
        float sn, cs;
        sincosf((float)s * inv_freq, &sn, &cs);
        tab[i] = make_float2(cs, sn);
    }
}

// ------- 128x128xK bf16 MFMA mainloop, BK=64 (2x32 stages per barrier pair) -------
// LDS: two 128x32 subtiles per operand (32 KB total), unpadded for DMA deposit.
__device__ __forceinline__ void gemm_mainloop(const u16* __restrict__ Ab,
                                              const u16* __restrict__ Bb, int K,
                                              u16* As, u16* Bs, int tid,
                                              f32x4 (&acc)[4][4]) {
    const int wave = tid >> 6, lane = tid & 63;
    const int col = lane & 15, quad = lane >> 4;
    const int wm = wave >> 1, wn = wave & 1;
    const int lrow = lane >> 2, lk = (lane & 3) * 8;
    u16* ldsA0 = As + (wave * 16) * 32;  // wave-uniform segment bases
    u16* ldsA1 = As + (64 + wave * 16) * 32;
    u16* ldsB0 = Bs + (wave * 16) * 32;
    u16* ldsB1 = Bs + (64 + wave * 16) * 32;
    const u16* gA0 = Ab + (size_t)(wave * 16 + lrow) * K + lk;
    const u16* gA1 = gA0 + (size_t)64 * K;
    const u16* gB0 = Bb + (size_t)(wave * 16 + lrow) * K + lk;
    const u16* gB1 = gB0 + (size_t)64 * K;
    for (int k0 = 0; k0 < K; k0 += 64) {
        if (k0) __syncthreads();
#pragma unroll
        for (int kh = 0; kh < 2; ++kh) {
            int ko = k0 + kh * 32;
            gl_lds16(gA0 + ko, ldsA0 + kh * 4096);
            gl_lds16(gA1 + ko, ldsA1 + kh * 4096);
            gl_lds16(gB0 + ko, ldsB0 + kh * 4096);
            gl_lds16(gB1 + ko, ldsB1 + kh * 4096);
        }
        __syncthreads();  // compiler drains vmcnt(0) before s_barrier
#pragma unroll
        for (int kh = 0; kh < 2; ++kh) {
            bf16x8 af[4], bfr[4];
#pragma unroll
            for (int mt = 0; mt < 4; ++mt)
                af[mt] = *(const bf16x8*)(As + kh * 4096 +
                                          (wm * 64 + mt * 16 + col) * 32 + quad * 8);
#pragma unroll
            for (int nt = 0; nt < 4; ++nt)
                bfr[nt] = *(const bf16x8*)(Bs + kh * 4096 +
                                           (wn * 64 + nt * 16 + col) * 32 + quad * 8);
#pragma unroll
            for (int mt = 0; mt < 4; ++mt)
#pragma unroll
                for (int nt = 0; nt < 4; ++nt)
                    acc[mt][nt] = __builtin_amdgcn_mfma_f32_16x16x32_bf16(
                        af[mt], bfr[nt], acc[mt][nt], 0, 0, 0);
        }
    }
}

// ---------------- QKV GEMM + bias + RoPE + head reshape ----------------
// Q additionally prescaled by 0.125*log2(e) so attention softmax is pure exp2.
// Region (q/k/v) is block-uniform: 128-col blocks never straddle a 1024 boundary.
__global__ __launch_bounds__(256) void k_gemm_qkv_rope(
    const u16* __restrict__ A, const u16* __restrict__ Bt,
    const float* __restrict__ bias, const float2* __restrict__ tab,
    u16* __restrict__ Qr, u16* __restrict__ Kr, u16* __restrict__ Vt) {
    __shared__ __align__(16) u16 smem[16384];  // mainloop: As|Bs ; epilogue: 128x128 tile
    u16* As = smem;
    u16* Bs = smem + 8192;
    const int K = 1024;
    int tid = threadIdx.x;
    int lane = tid & 63, wave = tid >> 6;
    int col = lane & 15, quad = lane >> 4;
    int wm = wave >> 1, wn = wave & 1;
    int mBase = blockIdx.y * 128;
    int nBase = blockIdx.x * 128;
    f32x4 acc[4][4] = {};
    gemm_mainloop(A + (size_t)mBase * K, Bt + (size_t)nBase * K, K, As, Bs, tid, acc);

    int region = nBase >> 10;  // 0=q, 1=k, 2=v (block-uniform)
    int n64 = nBase + wn * 64;
    int h = (n64 & 1023) >> 6;
    if (region < 2) {
        __syncthreads();  // mainloop LDS reads complete before tile overwrite
        float qs = (region == 0) ? 0.18033688011112042f : 1.0f;  // 0.125*log2(e)
#pragma unroll
        for (int nt = 0; nt < 2; ++nt) {
            int d1 = nt * 16 + col;  // 0..31
            float b1 = bias[n64 + d1];
            float b2 = bias[n64 + d1 + 32];
            int nl = wn * 64 + nt * 16 + col;
#pragma unroll
            for (int mt = 0; mt < 4; ++mt) {
                int mlb = wm * 64 + mt * 16 + quad * 4;
#pragma unroll
                for (int r = 0; r < 4; ++r) {
                    int mloc = mlb + r;
                    int s = (mBase + mloc) & 2047;
                    float2 t = tab[s * 32 + d1];
                    float t1 = acc[mt][nt][r] + b1;
                    float t2 = acc[mt][nt + 2][r] + b2;
                    int sw = (mloc & 7) << 3;  // 16B-chunk XOR swizzle
                    smem[mloc * 128 + (nl ^ sw)] = f2b((t1 * t.x - t2 * t.y) * qs);
                    smem[mloc * 128 + ((nl + 32) ^ sw)] = f2b((t2 * t.x + t1 * t.y) * qs);
                }
            }
        }
        __syncthreads();
        u16* outp = (region == 0) ? Qr : Kr;
#pragma unroll
        for (int p = 0; p < 8; ++p) {
            int lin = p * 256 + tid;   // 0..2047
            int mloc = lin >> 4;       // 0..127
            int c8 = (lin & 15) << 3;  // 0..120
            uint4 v = *(const uint4*)(smem + mloc * 128 + (c8 ^ ((mloc & 7) << 3)));
            int m = mBase + mloc;
            int s = m & 2047, b = m >> 11;
            int ng = (nBase & 1023) + c8;  // col within region
            *(uint4*)(outp + ((size_t)((b * 16 + (ng >> 6)) * 2048 + s)) * 64 +
                      (ng & 63)) = v;
        }
    } else {
        int b = mBase >> 11;     // block-uniform (mBase multiple of 128)
        int sb0 = mBase & 2047;  // s of tile row 0
#pragma unroll
        for (int nt = 0; nt < 4; ++nt) {
            int d = nt * 16 + col;
            float bv = bias[n64 + d];
            u16* vrow = Vt + ((size_t)((b * 16 + h) * 64 + d)) * 2048;
#pragma unroll
            for (int mt = 0; mt < 4; ++mt) {
                int s = sb0 + wm * 64 + mt * 16 + quad * 4;  // 4-aligned
                uint2 w;
                w.x = pk2(acc[mt][nt][0] + bv, acc[mt][nt][1] + bv);
                w.y = pk2(acc[mt][nt][2] + bv, acc[mt][nt][3] + bv);
                *(uint2*)(vrow + s) = w;
            }
        }
    }
}

// ---- attn K/V tile staging: async DMA, chunk-XOR swizzled (rule #21) ----
// LDS [64 rows][8 chunks of 16B]; data chunk c of row r at LDS chunk c ^ key(r);
// key_K(r)=(r&3)|(((r>>3)&1)<<2), key_V(d)=d&7 -- both equal (col&7) on reads.
__device__ __forceinline__ void stage_kv(const u16* __restrict__ Kt,
                                         const u16* __restrict__ Vtb, u16* KsB,
                                         u16* VsB, int wave, int lane) {
    int lr = lane >> 3;  // row within 8-row segment
    int lc = lane & 7;   // chunk slot
#pragma unroll
    for (int i = 0; i < 2; ++i) {
        int s = wave * 2 + i;  // K segment 0..7
        int r = s * 8 + lr;    // local key row 0..63
        int key = (r & 3) | (((r >> 3) & 1) << 2);
        gl_lds16(Kt + (size_t)r * 64 + ((lc ^ key) << 3), KsB + s * 512);
    }
#pragma unroll
    for (int i = 0; i < 2; ++i) {
        int s = wave * 2 + i;  // V segment 0..7
        int d = s * 8 + lr;    // local d row 0..63
        int key = d & 7;
        gl_lds16(Vtb + (size_t)d * 2048 + ((lc ^ key) << 3), VsB + s * 512);
    }
}

// ------------- flash attention (causal, transposed, permuted-row) -------------
// One block = one PAIR of 64-query tiles processed sequentially: phase 0 handles
// T=31-t, phase 1 handles T=t -> every block does exactly 33 key-tile iters
// (uniform work, no straggler tail). Grid 16x64 = 1024 blocks = 4/CU (LDS 32KB).
// XCD map: xcd=id&7, head=xcd*8+(w&7), t=w>>3 -- a head's 16 blocks share one
// XCD's L2 (FETCH 147->31MB r2 win). K/V double-buffered via async gl_lds DMA:
// tile j+1's 16 DMA ops (4/wave) issue before tile j's compute; end-of-iter
// __syncthreads drains vmcnt. T5 setprio wraps MFMA clusters (+4-7%, m191).
__global__ __launch_bounds__(256, 4) void k_attn(const u16* __restrict__ Qr,
                                                 const u16* __restrict__ Kr,
                                                 const u16* __restrict__ Vt,
                                                 u16* __restrict__ O) {
    __shared__ __align__(16) u16 Ks[2][4096];  // [buf][key][d] chunk-swizzled
    __shared__ __align__(16) u16 Vs[2][4096];  // [buf][d][key] chunk-swizzled
    int tid = threadIdx.x, wave = tid >> 6, lane = tid & 63;
    int col = lane & 15, quad = lane >> 4;
    int id = blockIdx.x + (blockIdx.y << 4);
    int xcd = id & 7, w = id >> 3;  // w: 0..127 within XCD
    int head = xcd * 8 + (w & 7);   // 0..63
    int tsel = w >> 3;              // 0..15
    int b = head >> 4, h = head & 15;
    size_t headQ = (size_t)head * 2048 * 64;
    size_t headV = (size_t)head * 64 * 2048;
    int prow = (col >> 2) * 8 + (col & 3);  // permuted row within 32
    int ck = col & 7;                       // read-side swizzle key

#pragma unroll 1
    for (int phase = 0; phase < 2; ++phase) {
        int T = phase ? tsel : 31 - tsel;  // key-tile count-1 for this q-tile
        int myq = T * 64 + wave * 16 + col;
        const u16* qp = Qr + headQ + (size_t)myq * 64;
        bf16x8 aq0 = *(const bf16x8*)(qp + quad * 8);
        bf16x8 aq1 = *(const bf16x8*)(qp + 32 + quad * 8);
        f32x4 o[4] = {};
        float l = 0.f;

        // prologue: stage key-tile 0 into buf 0 (prev phase ended with barrier)
        stage_kv(Kr + headQ, Vt + headV, Ks[0], Vs[0], wave, lane);
        __syncthreads();  // drains vmcnt(0): tile 0 deposited

        for (int j = 0; j <= T; ++j) {
            int cur = j & 1;
            if (j < T)  // async prefetch tile j+1 into other buffer
                stage_kv(Kr + headQ + ((size_t)(j + 1) << 12),
                         Vt + headV + (j + 1) * 64, Ks[cur ^ 1], Vs[cur ^ 1],
                         wave, lane);
            const u16* KsC = Ks[cur];
            const u16* VsC = Vs[cur];
            f32x4 s[4];
            __builtin_amdgcn_s_setprio(1);
#pragma unroll
            for (int nt = 0; nt < 4; ++nt) {
                const u16* kp = KsC + ((nt & 1) * 32 + (nt >> 1) * 4 + prow) * 64;
                bf16x8 ak0 = *(const bf16x8*)(kp + ((quad ^ ck) << 3));
                bf16x8 ak1 = *(const bf16x8*)(kp + (((quad + 4) ^ ck) << 3));
                f32x4 z = {};
                z = __builtin_amdgcn_mfma_f32_16x16x32_bf16(ak0, aq0, z, 0, 0, 0);
                s[nt] = __builtin_amdgcn_mfma_f32_16x16x32_bf16(ak1, aq1, z, 0, 0, 0);
            }
            __builtin_amdgcn_s_setprio(0);
            if (j == T) {  // diagonal mask
#pragma unroll
                for (int nt = 0; nt < 4; ++nt) {
                    int keyb = j * 64 + (nt & 1) * 32 + quad * 8 + (nt >> 1) * 4;
#pragma unroll
                    for (int r = 0; r < 4; ++r)
                        if (keyb + r > myq) s[nt][r] = -3.0e38f;
                }
            }
            unsigned P4[8];
#pragma unroll
            for (int nt = 0; nt < 4; ++nt) {
                float p0 = EXP2F(s[nt][0]);
                float p1 = EXP2F(s[nt][1]);
                float p2 = EXP2F(s[nt][2]);
                float p3 = EXP2F(s[nt][3]);
                l += (p0 + p1) + (p2 + p3);
                P4[2 * nt] = pk2(p0, p1);
                P4[2 * nt + 1] = pk2(p2, p3);
            }
            __builtin_amdgcn_s_setprio(1);
#pragma unroll
            for (int kk = 0; kk < 2; ++kk) {
                uint4 bw;
                bw.x = P4[2 * kk];
                bw.y = P4[2 * kk + 1];
                bw.z = P4[2 * kk + 4];
                bw.w = P4[2 * kk + 5];
                bf16x8 bp = __builtin_bit_cast(bf16x8, bw);
#pragma unroll
                for (int mt = 0; mt < 4; ++mt) {
                    bf16x8 av = *(const bf16x8*)(VsC + (mt * 16 + col) * 64 +
                                                 (((kk * 4 + quad) ^ ck) << 3));
                    o[mt] = __builtin_amdgcn_mfma_f32_16x16x32_bf16(av, bp, o[mt], 0, 0, 0);
                }
            }
            __builtin_amdgcn_s_setprio(0);
            __syncthreads();  // drains prefetch DMA + releases buffers
        }
        l += __shfl_xor(l, 16);
        l += __shfl_xor(l, 32);
        float inv = 1.0f / l;
        u16* orow = O + (size_t)(b * 2048 + myq) * 1024 + h * 64;
#pragma unroll
        for (int mt = 0; mt < 4; ++mt) {
            uint2 w2;
            w2.x = pk2(o[mt][0] * inv, o[mt][1] * inv);
            w2.y = pk2(o[mt][2] * inv, o[mt][3] * inv);
            *(uint2*)(orow + mt * 16 + quad * 4) = w2;
        }
    }
}

// ------- 128x64 proj mainloop: B stages only 64 rows; 4 waves, each 32M x 64N -------
// LDS: A 2x[128][32] (16KB) + B 2x[64][32] (8KB) = 24KB. Same 2-phase schedule
// as gemm_mainloop; 1024 blocks = 4/CU restores wave-level overlap.
__device__ __forceinline__ void proj_mainloop(const u16* __restrict__ Ab,
                                              const u16* __restrict__ Bb,
                                              u16* As, u16* Bs, int tid,
                                              f32x4 (&acc)[2][4]) {
    const int wave = tid >> 6, lane = tid & 63;
    const int col = lane & 15, quad = lane >> 4;
    const int lrow = lane >> 2, lk = (lane & 3) * 8;
    u16* ldsA0 = As + (wave * 16) * 32;  // wave-uniform segment bases
    u16* ldsA1 = As + (64 + wave * 16) * 32;
    u16* ldsB0 = Bs + (wave * 16) * 32;
    const u16* gA0 = Ab + (size_t)(wave * 16 + lrow) * 1024 + lk;
    const u16* gA1 = gA0 + (size_t)64 * 1024;
    const u16* gB0 = Bb + (size_t)(wave * 16 + lrow) * 1024 + lk;
    for (int k0 = 0; k0 < 1024; k0 += 64) {
        if (k0) __syncthreads();
#pragma unroll
        for (int kh = 0; kh < 2; ++kh) {
            int ko = k0 + kh * 32;
            gl_lds16(gA0 + ko, ldsA0 + kh * 4096);
            gl_lds16(gA1 + ko, ldsA1 + kh * 4096);
            gl_lds16(gB0 + ko, ldsB0 + kh * 2048);
        }
        __syncthreads();  // drains vmcnt(0) before s_barrier
#pragma unroll
        for (int kh = 0; kh < 2; ++kh) {
            bf16x8 af[2], bfr[4];
#pragma unroll
            for (int mt = 0; mt < 2; ++mt)
                af[mt] = *(const bf16x8*)(As + kh * 4096 +
                                          (wave * 32 + mt * 16 + col) * 32 + quad * 8);
#pragma unroll
            for (int nt = 0; nt < 4; ++nt)
                bfr[nt] = *(const bf16x8*)(Bs + kh * 2048 +
                                           (nt * 16 + col) * 32 + quad * 8);
#pragma unroll
            for (int mt = 0; mt < 2; ++mt)
#pragma unroll
                for (int nt = 0; nt < 4; ++nt)
                    acc[mt][nt] = __builtin_amdgcn_mfma_f32_16x16x32_bf16(
                        af[mt], bfr[nt], acc[mt][nt], 0, 0, 0);
        }
    }
}

// ---------------- output projection GEMM, 128x64 tiles (1024 blocks = 4/CU) ----------------
__global__ __launch_bounds__(256, 4) void k_gemm_proj(const u16* __restrict__ A,
                                                      const u16* __restrict__ Bt,
                                                      const float* __restrict__ bias,
                                                      float* __restrict__ out) {
    __shared__ __align__(16) u16 As[2 * 128 * 32];
    __shared__ __align__(16) u16 Bs[2 * 64 * 32];
    int tid = threadIdx.x;
    int lane = tid & 63, wave = tid >> 6;
    int col = lane & 15, quad = lane >> 4;
    int mBase = blockIdx.y * 128;  // 64 M-tiles
    int nBase = blockIdx.x * 64;   // 16 N-tiles
    f32x4 acc[2][4] = {};
    proj_mainloop(A + (size_t)mBase * 1024, Bt + (size_t)nBase * 1024, As, Bs, tid, acc);
#pragma unroll
    for (int nt = 0; nt < 4; ++nt) {
        int n = nBase + nt * 16 + col;
        float bv = bias[n];
#pragma unroll
        for (int mt = 0; mt < 2; ++mt) {
            int m = mBase + wave * 32 + mt * 16 + quad * 4;
#pragma unroll
            for (int r = 0; r < 4; ++r)
                out[(size_t)(m + r) * 1024 + n] = acc[mt][nt][r] + bv;
        }
    }
}

// ---------------- launch ----------------
// ws: x_bf@0 (16MB) wqkvT (6MB) wprojT (2MB) Qr Kr Vt AO (16MB each)
// rope table (512KB) aliases AO: consumed by qkv gemm, AO written later by attn.
extern "C" void kernel_launch(void* const* d_in, const int* in_sizes, int n_in,
                              void* d_out, int out_size, void* d_ws, size_t ws_size,
                              hipStream_t stream) {
    const float* x = (const float*)d_in[0];
    const float* w_qkv = (const float*)d_in[1];
    const float* b_qkv = (const float*)d_in[2];
    const float* w_proj = (const float*)d_in[3];
    const float* b_proj = (const float*)d_in[4];
    float* out = (float*)d_out;
    char* ws = (char*)d_ws;
    u16* x_bf = (u16*)(ws);
    u16* wqkvT = (u16*)(ws + 16777216);
    u16* wprojT = (u16*)(ws + 23068672);
    u16* Qr = (u16*)(ws + 25165824);
    u16* Kr = (u16*)(ws + 41943040);
    u16* Vt = (u16*)(ws + 58720256);
    u16* AO = (u16*)(ws + 75497472);
    float2* tab = (float2*)(ws + 75497472);  // alias AO (dead until k_attn)

    k_prep<<<5376, 256, 0, stream>>>(x, x_bf, w_qkv, wqkvT, w_proj, wprojT, tab);
    k_gemm_qkv_rope<<<dim3(24, 64), 256, 0, stream>>>(x_bf, wqkvT, b_qkv, tab, Qr, Kr, Vt);
    k_attn<<<dim3(16, 64), 256, 0, stream>>>(Qr, Kr, Vt, AO);
    k_gemm_proj<<<dim3(16, 64), 256, 0, stream>>>(AO, wprojT, b_proj, out);
}

// Round 11
// 251.375 us; speedup vs baseline: 5.5090x; 1.0114x over previous
//
#include <hip/hip_runtime.h>

typedef unsigned short u16;
typedef __bf16 bf16x8 __attribute__((ext_vector_type(8)));
typedef float f32x4 __attribute__((ext_vector_type(4)));

__device__ __forceinline__ u16 f2b(float f) {
    unsigned u = __builtin_bit_cast(unsigned, f);
    unsigned r = (u + 0x7fffu + ((u >> 16) & 1u)) >> 16;
    return (u16)r;
}
#if __has_builtin(__builtin_amdgcn_cvt_pk_bf16_f32)
typedef __bf16 bf16x2_t __attribute__((ext_vector_type(2)));
__device__ __forceinline__ unsigned pk2(float a, float b) {
    return __builtin_bit_cast(unsigned, __builtin_amdgcn_cvt_pk_bf16_f32(a, b));
}
#else
__device__ __forceinline__ unsigned pk2(float a, float b) {
    return (unsigned)f2b(a) | ((unsigned)f2b(b) << 16);
}
#endif
#if __has_builtin(__builtin_amdgcn_exp2f)
#define EXP2F(x) __builtin_amdgcn_exp2f(x)
#else
#define EXP2F(x) exp2f(x)
#endif

// async global->LDS 16B/lane; lds dest is wave-uniform base (+lane*16 by HW);
// global source IS per-lane (m173) -- swizzled layouts via pre-swizzled source.
__device__ __forceinline__ void gl_lds16(const u16* g, u16* l) {
    __builtin_amdgcn_global_load_lds(
        (const __attribute__((address_space(1))) unsigned*)(const void*)g,
        (__attribute__((address_space(3))) unsigned*)(void*)l, 16, 0, 0);
}

// -------- 64x64 transpose+convert helper: in[R][C] f32 -> out[C][R] bf16 --------
// Pad 66: write bank = (33c)%32 = c%32 -> 2 lanes/bank (free, m136).
__device__ __forceinline__ void transpose64(const float* __restrict__ in,
                                            u16* __restrict__ out, int R, int C,
                                            int tr, int tc, int tid, u16 (*tile)[66]) {
    for (int i = tid; i < 4096; i += 256) {
        int r = i >> 6, c = i & 63;
        tile[c][r] = f2b(in[(size_t)(tr + r) * C + tc + c]);
    }
    __syncthreads();
    for (int i = tid; i < 4096; i += 256) {
        int r = i >> 6, c = i & 63;
        out[(size_t)(tc + r) * R + tr + c] = tile[r][c];
    }
}

// ---------------- fused prep: convert x | transpose wqkv | transpose wproj | rope tab ----
__global__ __launch_bounds__(256) void k_prep(const float* __restrict__ x,
                                              u16* __restrict__ x_bf,
                                              const float* __restrict__ w_qkv,
                                              u16* __restrict__ wqkvT,
                                              const float* __restrict__ w_proj,
                                              u16* __restrict__ wprojT,
                                              float2* __restrict__ tab) {
    __shared__ u16 tile[64][66];
    int bid = blockIdx.x, tid = threadIdx.x;
    if (bid < 4096) {  // x: fp32 -> bf16, 8 elems/thread
        int i = bid * 256 + tid;
        const float4* p = (const float4*)(x + (size_t)i * 8);
        float4 a = p[0], b = p[1];
        u16 t[8] = {f2b(a.x), f2b(a.y), f2b(a.z), f2b(a.w),
                    f2b(b.x), f2b(b.y), f2b(b.z), f2b(b.w)};
        *(uint4*)(x_bf + (size_t)i * 8) = *(const uint4*)t;
    } else if (bid < 4864) {  // w_qkv [1024][3072] -> wqkvT [3072][1024]
        int q = bid - 4096;
        transpose64(w_qkv, wqkvT, 1024, 3072, (q / 48) * 64, (q % 48) * 64, tid, tile);
    } else if (bid < 5120) {  // w_proj [1024][1024] -> wprojT
        int q = bid - 4864;
        transpose64(w_proj, wprojT, 1024, 1024, (q / 16) * 64, (q % 16) * 64, tid, tile);
    } else {  // tab[s*32+d] = (cos,sin)(s * 10000^(-d/32))
        int i = (bid - 5120) * 256 + tid;  // 0..65535
        int s = i >> 5, d = i & 31;
        const float C0 = 0.4152410118609203f;  // log2(10000)/32
        float inv_freq = exp2f(-C0 * (float)d);
        float sn, cs;
        sincosf((float)s * inv_freq, &sn, &cs);
        tab[i] = make_float2(cs, sn);
    }
}

// ------- 128x128xK bf16 MFMA mainloop, BK=64 (2x32 stages per barrier pair) -------
__device__ __forceinline__ void gemm_mainloop(const u16* __restrict__ Ab,
                                              const u16* __restrict__ Bb, int K,
                                              u16* As, u16* Bs, int tid,
                                              f32x4 (&acc)[4][4]) {
    const int wave = tid >> 6, lane = tid & 63;
    const int col = lane & 15, quad = lane >> 4;
    const int wm = wave >> 1, wn = wave & 1;
    const int lrow = lane >> 2, lk = (lane & 3) * 8;
    u16* ldsA0 = As + (wave * 16) * 32;  // wave-uniform segment bases
    u16* ldsA1 = As + (64 + wave * 16) * 32;
    u16* ldsB0 = Bs + (wave * 16) * 32;
    u16* ldsB1 = Bs + (64 + wave * 16) * 32;
    const u16* gA0 = Ab + (size_t)(wave * 16 + lrow) * K + lk;
    const u16* gA1 = gA0 + (size_t)64 * K;
    const u16* gB0 = Bb + (size_t)(wave * 16 + lrow) * K + lk;
    const u16* gB1 = gB0 + (size_t)64 * K;
    for (int k0 = 0; k0 < K; k0 += 64) {
        if (k0) __syncthreads();
#pragma unroll
        for (int kh = 0; kh < 2; ++kh) {
            int ko = k0 + kh * 32;
            gl_lds16(gA0 + ko, ldsA0 + kh * 4096);
            gl_lds16(gA1 + ko, ldsA1 + kh * 4096);
            gl_lds16(gB0 + ko, ldsB0 + kh * 4096);
            gl_lds16(gB1 + ko, ldsB1 + kh * 4096);
        }
        __syncthreads();  // compiler drains vmcnt(0) before s_barrier
#pragma unroll
        for (int kh = 0; kh < 2; ++kh) {
            bf16x8 af[4], bfr[4];
#pragma unroll
            for (int mt = 0; mt < 4; ++mt)
                af[mt] = *(const bf16x8*)(As + kh * 4096 +
                                          (wm * 64 + mt * 16 + col) * 32 + quad * 8);
#pragma unroll
            for (int nt = 0; nt < 4; ++nt)
                bfr[nt] = *(const bf16x8*)(Bs + kh * 4096 +
                                           (wn * 64 + nt * 16 + col) * 32 + quad * 8);
#pragma unroll
            for (int mt = 0; mt < 4; ++mt)
#pragma unroll
                for (int nt = 0; nt < 4; ++nt)
                    acc[mt][nt] = __builtin_amdgcn_mfma_f32_16x16x32_bf16(
                        af[mt], bfr[nt], acc[mt][nt], 0, 0, 0);
        }
    }
}

// ---------------- QKV GEMM + bias + RoPE + head reshape ----------------
// Q additionally prescaled by 0.125*log2(e) so attention softmax is pure exp2.
__global__ __launch_bounds__(256) void k_gemm_qkv_rope(
    const u16* __restrict__ A, const u16* __restrict__ Bt,
    const float* __restrict__ bias, const float2* __restrict__ tab,
    u16* __restrict__ Qr, u16* __restrict__ Kr, u16* __restrict__ Vt) {
    __shared__ __align__(16) u16 smem[16384];  // mainloop: As|Bs ; epilogue: 128x128 tile
    u16* As = smem;
    u16* Bs = smem + 8192;
    const int K = 1024;
    int tid = threadIdx.x;
    int lane = tid & 63, wave = tid >> 6;
    int col = lane & 15, quad = lane >> 4;
    int wm = wave >> 1, wn = wave & 1;
    int mBase = blockIdx.y * 128;
    int nBase = blockIdx.x * 128;
    f32x4 acc[4][4] = {};
    gemm_mainloop(A + (size_t)mBase * K, Bt + (size_t)nBase * K, K, As, Bs, tid, acc);

    int region = nBase >> 10;  // 0=q, 1=k, 2=v (block-uniform)
    int n64 = nBase + wn * 64;
    int h = (n64 & 1023) >> 6;
    if (region < 2) {
        __syncthreads();  // mainloop LDS reads complete before tile overwrite
        float qs = (region == 0) ? 0.18033688011112042f : 1.0f;  // 0.125*log2(e)
#pragma unroll
        for (int nt = 0; nt < 2; ++nt) {
            int d1 = nt * 16 + col;  // 0..31
            float b1 = bias[n64 + d1];
            float b2 = bias[n64 + d1 + 32];
            int nl = wn * 64 + nt * 16 + col;
#pragma unroll
            for (int mt = 0; mt < 4; ++mt) {
                int mlb = wm * 64 + mt * 16 + quad * 4;
#pragma unroll
                for (int r = 0; r < 4; ++r) {
                    int mloc = mlb + r;
                    int s = (mBase + mloc) & 2047;
                    float2 t = tab[s * 32 + d1];
                    float t1 = acc[mt][nt][r] + b1;
                    float t2 = acc[mt][nt + 2][r] + b2;
                    int sw = (mloc & 7) << 3;  // 16B-chunk XOR swizzle
                    smem[mloc * 128 + (nl ^ sw)] = f2b((t1 * t.x - t2 * t.y) * qs);
                    smem[mloc * 128 + ((nl + 32) ^ sw)] = f2b((t2 * t.x + t1 * t.y) * qs);
                }
            }
        }
        __syncthreads();
        u16* outp = (region == 0) ? Qr : Kr;
#pragma unroll
        for (int p = 0; p < 8; ++p) {
            int lin = p * 256 + tid;   // 0..2047
            int mloc = lin >> 4;       // 0..127
            int c8 = (lin & 15) << 3;  // 0..120
            uint4 v = *(const uint4*)(smem + mloc * 128 + (c8 ^ ((mloc & 7) << 3)));
            int m = mBase + mloc;
            int s = m & 2047, b = m >> 11;
            int ng = (nBase & 1023) + c8;  // col within region
            *(uint4*)(outp + ((size_t)((b * 16 + (ng >> 6)) * 2048 + s)) * 64 +
                      (ng & 63)) = v;
        }
    } else {
        int b = mBase >> 11;     // block-uniform (mBase multiple of 128)
        int sb0 = mBase & 2047;  // s of tile row 0
#pragma unroll
        for (int nt = 0; nt < 4; ++nt) {
            int d = nt * 16 + col;
            float bv = bias[n64 + d];
            u16* vrow = Vt + ((size_t)((b * 16 + h) * 64 + d)) * 2048;
#pragma unroll
            for (int mt = 0; mt < 4; ++mt) {
                int s = sb0 + wm * 64 + mt * 16 + quad * 4;  // 4-aligned
                uint2 w;
                w.x = pk2(acc[mt][nt][0] + bv, acc[mt][nt][1] + bv);
                w.y = pk2(acc[mt][nt][2] + bv, acc[mt][nt][3] + bv);
                *(uint2*)(vrow + s) = w;
            }
        }
    }
}

// ---- attn K/V tile staging: async DMA, chunk-XOR swizzled (rule #21) ----
// LDS [64 rows][8 chunks of 16B]; data chunk c of row r at LDS chunk c ^ key(r);
// key_K(r)=(r&3)|(((r>>3)&1)<<2), key_V(d)=d&7 -- both equal (col&7) on reads.
// 2 DMA per wave per call.
__device__ __forceinline__ void stage_k(const u16* __restrict__ Kt, u16* KsB,
                                        int wave, int lane) {
    int lr = lane >> 3, lc = lane & 7;
#pragma unroll
    for (int i = 0; i < 2; ++i) {
        int s = wave * 2 + i;  // segment 0..7
        int r = s * 8 + lr;    // local key row 0..63
        int key = (r & 3) | (((r >> 3) & 1) << 2);
        gl_lds16(Kt + (size_t)r * 64 + ((lc ^ key) << 3), KsB + s * 512);
    }
}
__device__ __forceinline__ void stage_v(const u16* __restrict__ Vtb, u16* VsB,
                                        int wave, int lane) {
    int lr = lane >> 3, lc = lane & 7;
#pragma unroll
    for (int i = 0; i < 2; ++i) {
        int s = wave * 2 + i;  // segment 0..7
        int d = s * 8 + lr;    // local d row 0..63
        int key = d & 7;
        gl_lds16(Vtb + (size_t)d * 2048 + ((lc ^ key) << 3), VsB + s * 512);
    }
}

// ------------- flash attention: T4 counted-vmcnt pipeline (no per-iter drain) -------------
// r4 body (QK/softmax/PV/mask/layout identical); sync skeleton replaced:
// K triple-buffered (prefetch 2 ahead), V double-buffered (1 ahead, consumed
// mid-iter). Per iter: issue K(j+2),V(j+1) -> QK^T -> softmax ->
// s_waitcnt vmcnt(N), N = ops just issued (4/2/0) -- oldest-first semantics
// (m135) guarantee V(j)+K(j+1) landed while new prefetches stay in flight ->
// PV -> raw s_barrier (NO vmcnt(0) drain; per-wave counted wait + barrier =
// global completion; m218: counted-vs-drain0 = +38-73% on GEMM). sched_barrier
// after asm waits/barriers per rule #18. LDS 3*8+2*8=40KB -> still 4 blocks/CU.
// Tail degrades N 4->2->0, so each phase ends fully drained (phase-boundary +
// epilogue safe). Uniform 33 iters/block; XCD-L2 head map (r2: FETCH 147->31MB).
__global__ __launch_bounds__(256, 4) void k_attn(const u16* __restrict__ Qr,
                                                 const u16* __restrict__ Kr,
                                                 const u16* __restrict__ Vt,
                                                 u16* __restrict__ O) {
    __shared__ __align__(16) u16 Ks[3][4096];  // [buf][key][d] chunk-swizzled
    __shared__ __align__(16) u16 Vs[2][4096];  // [buf][d][key] chunk-swizzled
    int tid = threadIdx.x, wave = tid >> 6, lane = tid & 63;
    int col = lane & 15, quad = lane >> 4;
    int id = blockIdx.x + (blockIdx.y << 4);
    int xcd = id & 7, w = id >> 3;  // w: 0..127 within XCD
    int head = xcd * 8 + (w & 7);   // 0..63
    int tsel = w >> 3;              // 0..15
    int b = head >> 4, h = head & 15;
    size_t headQ = (size_t)head * 2048 * 64;
    size_t headV = (size_t)head * 64 * 2048;
    int prow = (col >> 2) * 8 + (col & 3);  // permuted row within 32
    int ck = col & 7;                       // read-side swizzle key
    const u16* Kh = Kr + headQ;
    const u16* Vh = Vt + headV;

#pragma unroll 1
    for (int phase = 0; phase < 2; ++phase) {
        int T = phase ? tsel : 31 - tsel;  // key-tile count-1 for this q-tile
        int myq = T * 64 + wave * 16 + col;
        const u16* qp = Qr + headQ + (size_t)myq * 64;
        bf16x8 aq0 = *(const bf16x8*)(qp + quad * 8);
        bf16x8 aq1 = *(const bf16x8*)(qp + 32 + quad * 8);
        f32x4 o[4] = {};
        float l = 0.f;

        // prologue: stage K0,V0,K1 (tile 1 always exists: T<=31). Wait leaves
        // K1's 2 ops in flight; prior phase ended fully drained + barriered.
        stage_k(Kh, Ks[0], wave, lane);
        stage_v(Vh, Vs[0], wave, lane);
        stage_k(Kh + (1 << 12), Ks[1], wave, lane);
        asm volatile("s_waitcnt vmcnt(2)" ::: "memory");
        __builtin_amdgcn_s_barrier();
        __builtin_amdgcn_sched_barrier(0);

        int kcur = 0;  // j % 3
        for (int j = 0; j <= T; ++j) {
            bool pfK = (j + 2 <= T);
            bool pfV = (j + 1 <= T);
            if (pfK)
                stage_k(Kh + ((size_t)(j + 2) << 12), Ks[kcur == 0 ? 2 : kcur - 1],
                        wave, lane);
            if (pfV) stage_v(Vh + (j + 1) * 64, Vs[(j + 1) & 1], wave, lane);
            const u16* KsC = Ks[kcur];
            const u16* VsC = Vs[j & 1];
            f32x4 s[4];
            __builtin_amdgcn_s_setprio(1);
#pragma unroll
            for (int nt = 0; nt < 4; ++nt) {
                const u16* kp = KsC + ((nt & 1) * 32 + (nt >> 1) * 4 + prow) * 64;
                bf16x8 ak0 = *(const bf16x8*)(kp + ((quad ^ ck) << 3));
                bf16x8 ak1 = *(const bf16x8*)(kp + (((quad + 4) ^ ck) << 3));
                f32x4 z = {};
                z = __builtin_amdgcn_mfma_f32_16x16x32_bf16(ak0, aq0, z, 0, 0, 0);
                s[nt] = __builtin_amdgcn_mfma_f32_16x16x32_bf16(ak1, aq1, z, 0, 0, 0);
            }
            __builtin_amdgcn_s_setprio(0);
            if (j == T) {  // diagonal mask
#pragma unroll
                for (int nt = 0; nt < 4; ++nt) {
                    int keyb = j * 64 + (nt & 1) * 32 + quad * 8 + (nt >> 1) * 4;
#pragma unroll
                    for (int r = 0; r < 4; ++r)
                        if (keyb + r > myq) s[nt][r] = -3.0e38f;
                }
            }
            unsigned P4[8];
#pragma unroll
            for (int nt = 0; nt < 4; ++nt) {
                float p0 = EXP2F(s[nt][0]);
                float p1 = EXP2F(s[nt][1]);
                float p2 = EXP2F(s[nt][2]);
                float p3 = EXP2F(s[nt][3]);
                l += (p0 + p1) + (p2 + p3);
                P4[2 * nt] = pk2(p0, p1);
                P4[2 * nt + 1] = pk2(p2, p3);
            }
            // counted wait: all but the N newest (this iter's prefetches) are
            // complete => V(j) [PV below] and K(j+1) [next QK] have landed.
            if (pfK)
                asm volatile("s_waitcnt vmcnt(4)" ::: "memory");
            else if (pfV)
                asm volatile("s_waitcnt vmcnt(2)" ::: "memory");
            else
                asm volatile("s_waitcnt vmcnt(0)" ::: "memory");
            __builtin_amdgcn_sched_barrier(0);
            __builtin_amdgcn_s_setprio(1);
#pragma unroll
            for (int kk = 0; kk < 2; ++kk) {
                uint4 bw;
                bw.x = P4[2 * kk];
                bw.y = P4[2 * kk + 1];
                bw.z = P4[2 * kk + 4];
                bw.w = P4[2 * kk + 5];
                bf16x8 bp = __builtin_bit_cast(bf16x8, bw);
#pragma unroll
                for (int mt = 0; mt < 4; ++mt) {
                    bf16x8 av = *(const bf16x8*)(VsC + (mt * 16 + col) * 64 +
                                                 (((kk * 4 + quad) ^ ck) << 3));
                    o[mt] = __builtin_amdgcn_mfma_f32_16x16x32_bf16(av, bp, o[mt], 0, 0, 0);
                }
            }
            __builtin_amdgcn_s_setprio(0);
            __builtin_amdgcn_s_barrier();  // raw: no drain; releases buffers
            __builtin_amdgcn_sched_barrier(0);
            kcur = (kcur == 2) ? 0 : kcur + 1;
        }
        l += __shfl_xor(l, 16);
        l += __shfl_xor(l, 32);
        float inv = 1.0f / l;
        u16* orow = O + (size_t)(b * 2048 + myq) * 1024 + h * 64;
#pragma unroll
        for (int mt = 0; mt < 4; ++mt) {
            uint2 w2;
            w2.x = pk2(o[mt][0] * inv, o[mt][1] * inv);
            w2.y = pk2(o[mt][2] * inv, o[mt][3] * inv);
            *(uint2*)(orow + mt * 16 + quad * 4) = w2;
        }
    }
}

// ------- 128x64 proj mainloop: B stages only 64 rows; 4 waves, each 32M x 64N -------
__device__ __forceinline__ void proj_mainloop(const u16* __restrict__ Ab,
                                              const u16* __restrict__ Bb,
                                              u16* As, u16* Bs, int tid,
                                              f32x4 (&acc)[2][4]) {
    const int wave = tid >> 6, lane = tid & 63;
    const int col = lane & 15, quad = lane >> 4;
    const int lrow = lane >> 2, lk = (lane & 3) * 8;
    u16* ldsA0 = As + (wave * 16) * 32;  // wave-uniform segment bases
    u16* ldsA1 = As + (64 + wave * 16) * 32;
    u16* ldsB0 = Bs + (wave * 16) * 32;
    const u16* gA0 = Ab + (size_t)(wave * 16 + lrow) * 1024 + lk;
    const u16* gA1 = gA0 + (size_t)64 * 1024;
    const u16* gB0 = Bb + (size_t)(wave * 16 + lrow) * 1024 + lk;
    for (int k0 = 0; k0 < 1024; k0 += 64) {
        if (k0) __syncthreads();
#pragma unroll
        for (int kh = 0; kh < 2; ++kh) {
            int ko = k0 + kh * 32;
            gl_lds16(gA0 + ko, ldsA0 + kh * 4096);
            gl_lds16(gA1 + ko, ldsA1 + kh * 4096);
            gl_lds16(gB0 + ko, ldsB0 + kh * 2048);
        }
        __syncthreads();  // drains vmcnt(0) before s_barrier
#pragma unroll
        for (int kh = 0; kh < 2; ++kh) {
            bf16x8 af[2], bfr[4];
#pragma unroll
            for (int mt = 0; mt < 2; ++mt)
                af[mt] = *(const bf16x8*)(As + kh * 4096 +
                                          (wave * 32 + mt * 16 + col) * 32 + quad * 8);
#pragma unroll
            for (int nt = 0; nt < 4; ++nt)
                bfr[nt] = *(const bf16x8*)(Bs + kh * 2048 +
                                           (nt * 16 + col) * 32 + quad * 8);
#pragma unroll
            for (int mt = 0; mt < 2; ++mt)
#pragma unroll
                for (int nt = 0; nt < 4; ++nt)
                    acc[mt][nt] = __builtin_amdgcn_mfma_f32_16x16x32_bf16(
                        af[mt], bfr[nt], acc[mt][nt], 0, 0, 0);
        }
    }
}

// ---------------- output projection GEMM, 128x64 tiles (1024 blocks = 4/CU) ----------------
__global__ __launch_bounds__(256, 4) void k_gemm_proj(const u16* __restrict__ A,
                                                      const u16* __restrict__ Bt,
                                                      const float* __restrict__ bias,
                                                      float* __restrict__ out) {
    __shared__ __align__(16) u16 As[2 * 128 * 32];
    __shared__ __align__(16) u16 Bs[2 * 64 * 32];
    int tid = threadIdx.x;
    int lane = tid & 63, wave = tid >> 6;
    int col = lane & 15, quad = lane >> 4;
    int mBase = blockIdx.y * 128;  // 64 M-tiles
    int nBase = blockIdx.x * 64;   // 16 N-tiles
    f32x4 acc[2][4] = {};
    proj_mainloop(A + (size_t)mBase * 1024, Bt + (size_t)nBase * 1024, As, Bs, tid, acc);
#pragma unroll
    for (int nt = 0; nt < 4; ++nt) {
        int n = nBase + nt * 16 + col;
        float bv = bias[n];
#pragma unroll
        for (int mt = 0; mt < 2; ++mt) {
            int m = mBase + wave * 32 + mt * 16 + quad * 4;
#pragma unroll
            for (int r = 0; r < 4; ++r)
                out[(size_t)(m + r) * 1024 + n] = acc[mt][nt][r] + bv;
        }
    }
}

// ---------------- launch ----------------
// ws: x_bf@0 (16MB) wqkvT (6MB) wprojT (2MB) Qr Kr Vt AO (16MB each)
// rope table (512KB) aliases AO: consumed by qkv gemm, AO written later by attn.
extern "C" void kernel_launch(void* const* d_in, const int* in_sizes, int n_in,
                              void* d_out, int out_size, void* d_ws, size_t ws_size,
                              hipStream_t stream) {
    const float* x = (const float*)d_in[0];
    const float* w_qkv = (const float*)d_in[1];
    const float* b_qkv = (const float*)d_in[2];
    const float* w_proj = (const float*)d_in[3];
    const float* b_proj = (const float*)d_in[4];
    float* out = (float*)d_out;
    char* ws = (char*)d_ws;
    u16* x_bf = (u16*)(ws);
    u16* wqkvT = (u16*)(ws + 16777216);
    u16* wprojT = (u16*)(ws + 23068672);
    u16* Qr = (u16*)(ws + 25165824);
    u16* Kr = (u16*)(ws + 41943040);
    u16* Vt = (u16*)(ws + 58720256);
    u16* AO = (u16*)(ws + 75497472);
    float2* tab = (float2*)(ws + 75497472);  // alias AO (dead until k_attn)

    k_prep<<<5376, 256, 0, stream>>>(x, x_bf, w_qkv, wqkvT, w_proj, wprojT, tab);
    k_gemm_qkv_rope<<<dim3(24, 64), 256, 0, stream>>>(x_bf, wqkvT, b_qkv, tab, Qr, Kr, Vt);
    k_attn<<<dim3(16, 64), 256, 0, stream>>>(Qr, Kr, Vt, AO);
    k_gemm_proj<<<dim3(16, 64), 256, 0, stream>>>(AO, wprojT, b_proj, out);
}